// Round 7
// baseline (159.328 us; speedup 1.0000x reference)
//
#include <hip/hip_runtime.h>
#include <hip/hip_bf16.h>
#include <cstdio>

typedef float f32x4 __attribute__((ext_vector_type(4)));
typedef float f32x16 __attribute__((ext_vector_type(16)));
typedef __bf16 bf16x8 __attribute__((ext_vector_type(8)));

static constexpr int Bn = 8, Nn = 2048, Dn = 512, Hn = 512;

__device__ __forceinline__ unsigned short f2bf(float x) {
    union { float f; unsigned int u; } v; v.f = x;
    unsigned int r = (v.u + 0x7FFFu + ((v.u >> 16) & 1u)) >> 16;
    return (unsigned short)r;
}
__device__ __forceinline__ float bf2f(unsigned short h) {
    union { unsigned int u; float f; } v; v.u = ((unsigned int)h) << 16;
    return v.f;
}

__device__ __forceinline__ void gload_lds16(const unsigned short* g, unsigned short* l) {
    __builtin_amdgcn_global_load_lds(
        (const __attribute__((address_space(1))) void*)g,
        (__attribute__((address_space(3))) void*)l,
        16, 0, 0);
}

__device__ __forceinline__ int xcd_swizzle(int lin, int nwg) {
    return (lin & 7) * (nwg >> 3) + (lin >> 3);   // all grids %8==0
}

// ---------------- cast x (f32 -> bf16), flat ----------------
__global__ void cast_x_kernel(const float* __restrict__ x, unsigned short* __restrict__ xb, int n) {
    int i = (blockIdx.x * blockDim.x + threadIdx.x) * 8;
    if (i >= n) return;
    float4 a = *(const float4*)(x + i);
    float4 b = *(const float4*)(x + i + 4);
    unsigned short tmp[8] = {f2bf(a.x), f2bf(a.y), f2bf(a.z), f2bf(a.w),
                             f2bf(b.x), f2bf(b.y), f2bf(b.z), f2bf(b.w)};
    *(uint4*)(xb + i) = *(const uint4*)tmp;
}

// ---- weight transpose+cast: z=0 -> Wq, z=1 -> Wk; f32 [D][H] -> bf16 [H][D] ----
__global__ __launch_bounds__(256) void transpose_cast_w(
    const float* __restrict__ Wq, const float* __restrict__ Wk,
    unsigned short* __restrict__ out)
{
    __shared__ float tile[64][65];
    const int z = blockIdx.z;
    const float* inb = z ? Wk : Wq;
    unsigned short* outb = out + (size_t)z * Hn * Dn;
    const int r0 = blockIdx.y * 64, c0 = blockIdx.x * 64;
    const int tx = threadIdx.x & 63, ty = threadIdx.x >> 6;
#pragma unroll
    for (int p = 0; p < 64; p += 4) {
        const int r = p + ty;
        tile[r][tx] = inb[(size_t)(r0 + r) * Hn + c0 + tx];
    }
    __syncthreads();
#pragma unroll
    for (int p = 0; p < 64; p += 4) {
        const int oc = p + ty;
        outb[(size_t)(c0 + oc) * Dn + r0 + tx] = f2bf(tile[tx][oc]);
    }
}

// ---- xsT[b][d][j] = bf16(x_bf16[b][j][d] / s[b][j]) ----
__global__ __launch_bounds__(256) void transpose_scale_bf16(
    const unsigned short* __restrict__ xb, unsigned short* __restrict__ out,
    const float* __restrict__ s)
{
    __shared__ unsigned short tile[64][65];
    const int z = blockIdx.z;
    const unsigned short* inb = xb + (size_t)z * Nn * Dn;
    unsigned short* ob = out + (size_t)z * Nn * Dn;
    const int j0 = blockIdx.y * 64, d0 = blockIdx.x * 64;
    const int tx = threadIdx.x & 63, ty = threadIdx.x >> 6;
#pragma unroll
    for (int p = 0; p < 64; p += 4) {
        const int r = p + ty;
        tile[r][tx] = inb[(size_t)(j0 + r) * Dn + d0 + tx];
    }
    __syncthreads();
    const float sv = s[(size_t)z * Nn + j0 + tx];
#pragma unroll
    for (int p = 0; p < 64; p += 4) {
        const int oc = p + ty;
        ob[(size_t)(d0 + oc) * Nn + j0 + tx] = f2bf(bf2f(tile[tx][oc]) / sv);
    }
}

// ---------------- combine per-block partial column sums ----------------
__global__ void combine_s_kernel(const float* __restrict__ s_part, float* __restrict__ s,
                                 int nblk, int total) {
    int i = blockIdx.x * blockDim.x + threadIdx.x;
    if (i >= total) return;
    int z = i >> 11, j = i & (Nn - 1);
    float acc = 0.f;
    for (int p = 0; p < nblk; ++p) acc += s_part[((size_t)z * nblk + p) * Nn + j];
    s[i] = acc;
}

// ======== 128x128 2-phase dbuf GEMM (C = A*B^T), 32x32x16 MFMA ========
// R4 gemm_pv skeleton (proven: 0 conflicts, 2 blocks/CU, STAGE-before-compute,
// one vmcnt(0)+barrier per K-tile) with the MFMA upgraded to 32x32x16
// (17% fewer matrix-pipe cycles/FLOP, 16 instrs/K-tile/wave vs 32).
// LDS rows 128B (BK=64); 16B chunk c of row r stored at c^(r&7) (involution,
// pre-applied to the global source). Frag reads use pos = (kq*2+h)^(r&7) —
// same position function the 16x16 kernel measured conflict-free.
// Wave grid 2x2, wave tile 64x64 = 2x2 frags of 32x32 (acc f32x16[2][2]).
// C/D layout (m74/m101): col=lane&31, row=(reg&3)+8*(reg>>2)+4*(lane>>5).
// MODE 0: C bf16 + bias split | MODE 1: C bf16=exp(acc) + col-sum partials
// MODE 2: C f32
template<int MODE>
__global__ __launch_bounds__(256, 2) void gemd(
    const unsigned short* __restrict__ A, long long sA, int lda,
    const unsigned short* __restrict__ Bt, long long sB, int ldb,
    void* __restrict__ Cp, long long sC,
    const float* __restrict__ bias, const float* __restrict__ bias2, int bsplit,
    float* __restrict__ s_part,
    int M, int N, int K, int gx, int gy)
{
    __shared__ unsigned short As[2][128 * 64];
    __shared__ unsigned short Bs[2][128 * 64];

    const int lin = xcd_swizzle(blockIdx.x, gridDim.x);
    const int bz = lin / (gx * gy);
    const int rem = lin - bz * gx * gy;
    const int by = rem / gx;
    const int bx = rem - by * gx;

    const unsigned short* Ab = A + (size_t)bz * sA;
    const unsigned short* Bb = Bt + (size_t)bz * sB;
    const int i0 = by * 128, j0 = bx * 128;

    const int t = threadIdx.x;
    const int lane = t & 63;
    const int wave = t >> 6;
    const int wm = wave >> 1, wn = wave & 1;   // wave tile 64x64
    const int r5 = lane & 31, h = lane >> 5;

    // frag read addressing (byte offsets into a [128][64] bf16 tile)
    const int arow = (wm * 64 + r5) * 128;
    const int brow = (wn * 64 + r5) * 128;
    int csw[4];
#pragma unroll
    for (int kq = 0; kq < 4; ++kq) csw[kq] = ((kq * 2 + h) ^ (r5 & 7)) * 16;

    f32x16 acc[2][2];
#pragma unroll
    for (int af = 0; af < 2; ++af)
#pragma unroll
        for (int bf = 0; bf < 2; ++bf)
#pragma unroll
            for (int r = 0; r < 16; ++r) acc[af][bf][r] = 0.f;

    // staging geometry (identical to proven R4 kernel)
    const int rbase = wave * 32;
    const int lrow = lane >> 3;
    const int gch = (lane & 7) ^ lrow;

#define STAGE(s, ktv)                                                          \
    {                                                                          \
        _Pragma("unroll")                                                      \
        for (int i = 0; i < 4; ++i) {                                          \
            const int r = rbase + i * 8 + lrow;                                \
            gload_lds16(Ab + (size_t)(i0 + r) * lda + (ktv) + gch * 8,         \
                        &As[s][(rbase + i * 8) * 64]);                         \
            gload_lds16(Bb + (size_t)(j0 + r) * ldb + (ktv) + gch * 8,         \
                        &Bs[s][(rbase + i * 8) * 64]);                         \
        }                                                                      \
    }

    STAGE(0, 0);
    asm volatile("s_waitcnt vmcnt(0)" ::: "memory");
    asm volatile("s_barrier" ::: "memory");

    const int NT = K >> 6;
    for (int T = 0; T < NT; ++T) {
        const int cur = T & 1;
        if (T + 1 < NT) STAGE(cur ^ 1, (T + 1) * 64);
#pragma unroll
        for (int kq = 0; kq < 4; ++kq) {
            bf16x8 a0 = *(const bf16x8*)((const char*)&As[cur][0] + arow + csw[kq]);
            bf16x8 a1 = *(const bf16x8*)((const char*)&As[cur][0] + arow + 4096 + csw[kq]);
            bf16x8 b0 = *(const bf16x8*)((const char*)&Bs[cur][0] + brow + csw[kq]);
            bf16x8 b1 = *(const bf16x8*)((const char*)&Bs[cur][0] + brow + 4096 + csw[kq]);
            __builtin_amdgcn_s_setprio(1);
            acc[0][0] = __builtin_amdgcn_mfma_f32_32x32x16_bf16(a0, b0, acc[0][0], 0, 0, 0);
            acc[0][1] = __builtin_amdgcn_mfma_f32_32x32x16_bf16(a0, b1, acc[0][1], 0, 0, 0);
            acc[1][0] = __builtin_amdgcn_mfma_f32_32x32x16_bf16(a1, b0, acc[1][0], 0, 0, 0);
            acc[1][1] = __builtin_amdgcn_mfma_f32_32x32x16_bf16(a1, b1, acc[1][1], 0, 0, 0);
            __builtin_amdgcn_s_setprio(0);
        }
        asm volatile("s_waitcnt vmcnt(0)" ::: "memory");
        asm volatile("s_barrier" ::: "memory");
    }
#undef STAGE

    // epilogue; output row = i0 + wm*64 + af*32 + (reg&3) + 8*(reg>>2) + 4*h
    const int col0 = j0 + wn * 64 + r5;
    if (MODE == 0) {
        unsigned short* C = (unsigned short*)Cp;
        float bv[2];
#pragma unroll
        for (int bf = 0; bf < 2; ++bf) {
            const int col = col0 + bf * 32;
            bv[bf] = (col < bsplit) ? bias[col] : bias2[col - bsplit];
        }
#pragma unroll
        for (int af = 0; af < 2; ++af)
#pragma unroll
            for (int reg = 0; reg < 16; ++reg) {
                const int row = i0 + wm * 64 + af * 32 + (reg & 3) + 8 * (reg >> 2) + 4 * h;
                unsigned short* Crow = C + (size_t)row * N + col0;
#pragma unroll
                for (int bf = 0; bf < 2; ++bf)
                    Crow[bf * 32] = f2bf(acc[af][bf][reg] + bv[bf]);
            }
    } else if (MODE == 1) {
        unsigned short* C = (unsigned short*)Cp + (size_t)bz * sC;
        float cs[2] = {0.f, 0.f};
#pragma unroll
        for (int af = 0; af < 2; ++af)
#pragma unroll
            for (int reg = 0; reg < 16; ++reg) {
                const int row = i0 + wm * 64 + af * 32 + (reg & 3) + 8 * (reg >> 2) + 4 * h;
                unsigned short* Crow = C + (size_t)row * N + col0;
#pragma unroll
                for (int bf = 0; bf < 2; ++bf) {
                    const float e = __expf(acc[af][bf][reg]);
                    const unsigned short hh = f2bf(e);
                    Crow[bf * 32] = hh;
                    cs[bf] += bf2f(hh);   // sum rounded value: num/denom consistency
                }
            }
        // lane l and l^32 cover complementary row halves of this wave's 64 rows
#pragma unroll
        for (int bf = 0; bf < 2; ++bf) cs[bf] += __shfl_xor(cs[bf], 32);
        __syncthreads();
        float* red = (float*)&As[0][0];   // [2][128] f32
        if (h == 0) {
#pragma unroll
            for (int bf = 0; bf < 2; ++bf)
                red[wm * 128 + wn * 64 + bf * 32 + r5] = cs[bf];
        }
        __syncthreads();
        if (t < 128)
            s_part[((size_t)bz * gy + by) * Nn + j0 + t] = red[t] + red[128 + t];
    } else {
        float* C = (float*)Cp + (size_t)bz * sC;
#pragma unroll
        for (int af = 0; af < 2; ++af)
#pragma unroll
            for (int reg = 0; reg < 16; ++reg) {
                const int row = i0 + wm * 64 + af * 32 + (reg & 3) + 8 * (reg >> 2) + 4 * h;
                float* Crow = C + (size_t)row * N + col0;
#pragma unroll
                for (int bf = 0; bf < 2; ++bf)
                    Crow[bf * 32] = acc[af][bf][reg];
            }
    }
}

extern "C" void kernel_launch(void* const* d_in, const int* in_sizes, int n_in,
                              void* d_out, int out_size, void* d_ws, size_t ws_size,
                              hipStream_t stream) {
    const float* x  = (const float*)d_in[0];
    const float* Wq = (const float*)d_in[1];
    const float* bq = (const float*)d_in[2];
    const float* Wk = (const float*)d_in[3];
    const float* bk = (const float*)d_in[4];
    float* out = (float*)d_out;

    // ws layout (116 MB): xsT reuses qk's space (qk dead after energy GEMM)
    char* ws = (char*)d_ws;
    unsigned short* xb    = (unsigned short*)(ws);                               // 0..16 MB
    unsigned short* qk    = (unsigned short*)(ws + (16ull << 20));               // 16..48 MB [16384][1024]
    unsigned short* xsT   = (unsigned short*)(ws + (16ull << 20));               // reuse (written step 6)
    unsigned short* WqkT  = (unsigned short*)(ws + (48ull << 20));               // 48..49 MB [1024][512]
    float*          s_prt = (float*)(ws + (49ull << 20));                        // 49..51 MB
    float*          s     = (float*)(ws + (51ull << 20));                        // 64 KB
    unsigned short* expE  = (unsigned short*)(ws + (52ull << 20));               // 52..116 MB
    if (ws_size < (116ull << 20)) {
        fprintf(stderr, "WS TOO SMALL: have %zu need %llu\n", ws_size, (116ull << 20));
    }

    // 1) xb = bf16(x)
    cast_x_kernel<<<dim3((Bn * Nn * Dn) / (8 * 256)), 256, 0, stream>>>(x, xb, Bn * Nn * Dn);
    // 2) WqkT = bf16([Wq; Wk]^T)
    transpose_cast_w<<<dim3(Hn / 64, Dn / 64, 2), 256, 0, stream>>>(Wq, Wk, WqkT);
    // 3) qk = xb @ [Wq|Wk] + [bq|bk]   (M=16384, N=1024, K=512) — 8 x 128 = 1024 blocks
    {
        const int gx = (2 * Hn) / 128, gy = (Bn * Nn) / 128;
        gemd<0><<<dim3(gx * gy), 256, 0, stream>>>(
            xb, 0, Dn, WqkT, 0, Dn, qk, 0, bq, bk, Hn, nullptr,
            Bn * Nn, 2 * Hn, Dn, gx, gy);
    }
    // 4) expE = exp(q @ k^T) + col-sum partials (per batch; M=N=2048, K=512) — 16x16x8 = 2048 blocks
    {
        const int gx = Nn / 128, gy = Nn / 128;
        gemd<1><<<dim3(gx * gy * Bn), 256, 0, stream>>>(
            qk, (long long)Nn * 2 * Hn, 2 * Hn,               // q = qk[:, 0:512]
            qk + Hn, (long long)Nn * 2 * Hn, 2 * Hn,          // k = qk[:, 512:1024]
            expE, (long long)Nn * Nn, nullptr, nullptr, 0, s_prt,
            Nn, Nn, Hn, gx, gy);
    }
    // 5) s[b][j] = sum of partials (16 m-blocks per batch)
    combine_s_kernel<<<dim3((Bn * Nn) / 256), 256, 0, stream>>>(s_prt, s, Nn / 128, Bn * Nn);
    // 6) xsT[b][d][j] = bf16(xb[b][j][d] / s[b][j])  (bf16 source; overwrites dead qk)
    transpose_scale_bf16<<<dim3(Dn / 64, Nn / 64, Bn), 256, 0, stream>>>(xb, xsT, s);
    // 7) out = expE @ xsT^T   (per batch; M=2048, N=512, K=2048) — 4 x 16 x 8 = 512 blocks
    {
        const int gx = Dn / 128, gy = Nn / 128;
        gemd<2><<<dim3(gx * gy * Bn), 256, 0, stream>>>(
            expE, (long long)Nn * Nn, Nn, xsT, (long long)Dn * Nn, Nn,
            out, (long long)Nn * Dn, nullptr, nullptr, 0, nullptr,
            Nn, Dn, Nn, gx, gy);
    }
}

// Round 8
// 140.183 us; speedup vs baseline: 1.1366x; 1.1366x over previous
//
#include <hip/hip_runtime.h>
#include <hip/hip_bf16.h>
#include <cstdio>

typedef float f32x4 __attribute__((ext_vector_type(4)));
typedef __bf16 bf16x8 __attribute__((ext_vector_type(8)));

static constexpr int Bn = 8, Nn = 2048, Dn = 512, Hn = 512;

__device__ __forceinline__ unsigned short f2bf(float x) {
    union { float f; unsigned int u; } v; v.f = x;
    unsigned int r = (v.u + 0x7FFFu + ((v.u >> 16) & 1u)) >> 16;
    return (unsigned short)r;
}
__device__ __forceinline__ float bf2f(unsigned short h) {
    union { unsigned int u; float f; } v; v.u = ((unsigned int)h) << 16;
    return v.f;
}

__device__ __forceinline__ void gload_lds16(const unsigned short* g, unsigned short* l) {
    __builtin_amdgcn_global_load_lds(
        (const __attribute__((address_space(1))) void*)g,
        (__attribute__((address_space(3))) void*)l,
        16, 0, 0);
}

__device__ __forceinline__ int xcd_swizzle(int lin, int nwg) {
    return (lin & 7) * (nwg >> 3) + (lin >> 3);   // all grids %8==0
}

// ---------------- cast x (f32 -> bf16), flat ----------------
__global__ void cast_x_kernel(const float* __restrict__ x, unsigned short* __restrict__ xb, int n) {
    int i = (blockIdx.x * blockDim.x + threadIdx.x) * 8;
    if (i >= n) return;
    float4 a = *(const float4*)(x + i);
    float4 b = *(const float4*)(x + i + 4);
    unsigned short tmp[8] = {f2bf(a.x), f2bf(a.y), f2bf(a.z), f2bf(a.w),
                             f2bf(b.x), f2bf(b.y), f2bf(b.z), f2bf(b.w)};
    *(uint4*)(xb + i) = *(const uint4*)tmp;
}

// ---- weight transpose+cast: z=0 -> Wq, z=1 -> Wk; f32 [D][H] -> bf16 [H][D] ----
__global__ __launch_bounds__(256) void transpose_cast_w(
    const float* __restrict__ Wq, const float* __restrict__ Wk,
    unsigned short* __restrict__ out)
{
    __shared__ float tile[64][65];
    const int z = blockIdx.z;
    const float* inb = z ? Wk : Wq;
    unsigned short* outb = out + (size_t)z * Hn * Dn;
    const int r0 = blockIdx.y * 64, c0 = blockIdx.x * 64;
    const int tx = threadIdx.x & 63, ty = threadIdx.x >> 6;
#pragma unroll
    for (int p = 0; p < 64; p += 4) {
        const int r = p + ty;
        tile[r][tx] = inb[(size_t)(r0 + r) * Hn + c0 + tx];
    }
    __syncthreads();
#pragma unroll
    for (int p = 0; p < 64; p += 4) {
        const int oc = p + ty;
        outb[(size_t)(c0 + oc) * Dn + r0 + tx] = f2bf(tile[tx][oc]);
    }
}

// ---- xsT[b][d][j] = bf16(x_bf16[b][j][d] / s[b][j]) ----
__global__ __launch_bounds__(256) void transpose_scale_bf16(
    const unsigned short* __restrict__ xb, unsigned short* __restrict__ out,
    const float* __restrict__ s)
{
    __shared__ unsigned short tile[64][65];
    const int z = blockIdx.z;
    const unsigned short* inb = xb + (size_t)z * Nn * Dn;
    unsigned short* ob = out + (size_t)z * Nn * Dn;
    const int j0 = blockIdx.y * 64, d0 = blockIdx.x * 64;
    const int tx = threadIdx.x & 63, ty = threadIdx.x >> 6;
#pragma unroll
    for (int p = 0; p < 64; p += 4) {
        const int r = p + ty;
        tile[r][tx] = inb[(size_t)(j0 + r) * Dn + d0 + tx];
    }
    __syncthreads();
    const float sv = s[(size_t)z * Nn + j0 + tx];
#pragma unroll
    for (int p = 0; p < 64; p += 4) {
        const int oc = p + ty;
        ob[(size_t)(d0 + oc) * Nn + j0 + tx] = f2bf(bf2f(tile[tx][oc]) / sv);
    }
}

// ---------------- combine per-block partial column sums ----------------
__global__ void combine_s_kernel(const float* __restrict__ s_part, float* __restrict__ s,
                                 int nblk, int total) {
    int i = blockIdx.x * blockDim.x + threadIdx.x;
    if (i >= total) return;
    int z = i >> 11, j = i & (Nn - 1);
    float acc = 0.f;
    for (int p = 0; p < nblk; ++p) acc += s_part[((size_t)z * nblk + p) * Nn + j];
    s[i] = acc;
}

// ======= 128x128 single-buffer 2-barrier GEMM (R2-proven: best measured) =======
// C = A * B^T; A [M][lda] bf16 (+z*sA), Bt [N][ldb] bf16 (+z*sB). BK=64.
// global_load_lds w16 staging, source pre-permuted chunk^=lrow (involution);
// reads pos = ((kk>>3)+g) ^ (row&7) — the ONLY pattern measured conflict-free
// this session (R7's 32x32 variant: 4.2M conflicts; R6's 64B rows: 3.1M).
// Epilogue: nf-innermost stores (R4-proven: WRITE 75->66 MB on energy).
// MODE 0: C bf16 + bias split | MODE 1: C bf16=exp(acc) + col-sum partials
// MODE 2: C f32
template<int MODE>
__global__ __launch_bounds__(256, 2) void gemm_bt(
    const unsigned short* __restrict__ A, long long sA, int lda,
    const unsigned short* __restrict__ Bt, long long sB, int ldb,
    void* __restrict__ Cp, long long sC,
    const float* __restrict__ bias, const float* __restrict__ bias2, int bsplit,
    float* __restrict__ s_part,
    int M, int N, int K, int gx, int gy)
{
    __shared__ unsigned short As[128 * 64];
    __shared__ unsigned short Bs[128 * 64];
    __shared__ float s_red[256];

    const int lin = xcd_swizzle(blockIdx.x, gridDim.x);
    const int bz = lin / (gx * gy);
    const int rem = lin - bz * gx * gy;
    const int by = rem / gx;
    const int bx = rem - by * gx;

    const unsigned short* Ab = A + (size_t)bz * sA;
    const unsigned short* Bb = Bt + (size_t)bz * sB;
    const int i0 = by * 128, j0 = bx * 128;

    const int t = threadIdx.x;
    const int lane = t & 63;
    const int wave = t >> 6;
    const int wr = wave >> 1, wc = wave & 1;
    const int l15 = lane & 15, g = lane >> 4;

    f32x4 acc[4][4];
    const f32x4 zero4 = {0.f, 0.f, 0.f, 0.f};
#pragma unroll
    for (int mi = 0; mi < 4; ++mi)
#pragma unroll
        for (int ni = 0; ni < 4; ++ni) acc[mi][ni] = zero4;

    const int rbase = wave * 32;
    const int lrow = lane >> 3;
    const int gch = (lane & 7) ^ lrow;

    for (int kt = 0; kt < K; kt += 64) {
#pragma unroll
        for (int i = 0; i < 4; ++i) {
            const int r = rbase + i * 8 + lrow;
            gload_lds16(Ab + (size_t)(i0 + r) * lda + kt + gch * 8, As + (rbase + i * 8) * 64);
            gload_lds16(Bb + (size_t)(j0 + r) * ldb + kt + gch * 8, Bs + (rbase + i * 8) * 64);
        }
        __syncthreads();
#pragma unroll
        for (int kk = 0; kk < 64; kk += 32) {
            const int sl0 = (kk >> 3) + g;
            bf16x8 af[4], bfr[4];
#pragma unroll
            for (int mi = 0; mi < 4; ++mi) {
                const int row = wr * 64 + mi * 16 + l15;
                af[mi] = *(const bf16x8*)(As + row * 64 + ((sl0 ^ (row & 7)) * 8));
            }
#pragma unroll
            for (int ni = 0; ni < 4; ++ni) {
                const int row = wc * 64 + ni * 16 + l15;
                bfr[ni] = *(const bf16x8*)(Bs + row * 64 + ((sl0 ^ (row & 7)) * 8));
            }
#pragma unroll
            for (int mi = 0; mi < 4; ++mi)
#pragma unroll
                for (int ni = 0; ni < 4; ++ni)
                    acc[mi][ni] = __builtin_amdgcn_mfma_f32_16x16x32_bf16(af[mi], bfr[ni], acc[mi][ni], 0, 0, 0);
        }
        __syncthreads();
    }

    const int col0 = j0 + wc * 64 + l15;
    if (MODE == 0) {
        unsigned short* C = (unsigned short*)Cp;
        float bv[4];
#pragma unroll
        for (int ni = 0; ni < 4; ++ni) {
            const int col = col0 + ni * 16;
            bv[ni] = (col < bsplit) ? bias[col] : bias2[col - bsplit];
        }
#pragma unroll
        for (int mi = 0; mi < 4; ++mi) {
            const int rb = i0 + wr * 64 + mi * 16 + g * 4;
#pragma unroll
            for (int r = 0; r < 4; ++r) {
                unsigned short* Crow = C + (size_t)(rb + r) * N + col0;
#pragma unroll
                for (int ni = 0; ni < 4; ++ni)
                    Crow[ni * 16] = f2bf(acc[mi][ni][r] + bv[ni]);
            }
        }
    } else if (MODE == 1) {
        unsigned short* C = (unsigned short*)Cp + (size_t)bz * sC;
        float cs[4] = {0.f, 0.f, 0.f, 0.f};
#pragma unroll
        for (int mi = 0; mi < 4; ++mi) {
            const int rb = i0 + wr * 64 + mi * 16 + g * 4;
#pragma unroll
            for (int r = 0; r < 4; ++r) {
                unsigned short* Crow = C + (size_t)(rb + r) * N + col0;
#pragma unroll
                for (int ni = 0; ni < 4; ++ni) {
                    const float e = __expf(acc[mi][ni][r]);
                    const unsigned short h = f2bf(e);
                    Crow[ni * 16] = h;
                    cs[ni] += bf2f(h);   // sum rounded value: num/denom consistency
                }
            }
        }
#pragma unroll
        for (int ni = 0; ni < 4; ++ni) {
            cs[ni] += __shfl_xor(cs[ni], 16);
            cs[ni] += __shfl_xor(cs[ni], 32);
        }
        if (g == 0) {
#pragma unroll
            for (int ni = 0; ni < 4; ++ni)
                s_red[wr * 128 + wc * 64 + ni * 16 + l15] = cs[ni];
        }
        __syncthreads();
        if (t < 128) {
            const float sp = s_red[t] + s_red[128 + t];
            s_part[((size_t)bz * gy + by) * Nn + j0 + t] = sp;
        }
    } else {
        float* C = (float*)Cp + (size_t)bz * sC;
#pragma unroll
        for (int mi = 0; mi < 4; ++mi) {
            const int rb = i0 + wr * 64 + mi * 16 + g * 4;
#pragma unroll
            for (int r = 0; r < 4; ++r) {
                float* Crow = C + (size_t)(rb + r) * N + col0;
#pragma unroll
                for (int ni = 0; ni < 4; ++ni)
                    Crow[ni * 16] = acc[mi][ni][r];
            }
        }
    }
}

extern "C" void kernel_launch(void* const* d_in, const int* in_sizes, int n_in,
                              void* d_out, int out_size, void* d_ws, size_t ws_size,
                              hipStream_t stream) {
    const float* x  = (const float*)d_in[0];
    const float* Wq = (const float*)d_in[1];
    const float* bq = (const float*)d_in[2];
    const float* Wk = (const float*)d_in[3];
    const float* bk = (const float*)d_in[4];
    float* out = (float*)d_out;

    // ws layout (116 MB): xsT reuses qk's space (qk dead after energy GEMM)
    char* ws = (char*)d_ws;
    unsigned short* xb    = (unsigned short*)(ws);                               // 0..16 MB
    unsigned short* qk    = (unsigned short*)(ws + (16ull << 20));               // 16..48 MB [16384][1024]
    unsigned short* xsT   = (unsigned short*)(ws + (16ull << 20));               // reuse (written step 6)
    unsigned short* WqkT  = (unsigned short*)(ws + (48ull << 20));               // 48..49 MB [1024][512]
    float*          s_prt = (float*)(ws + (49ull << 20));                        // 49..51 MB
    float*          s     = (float*)(ws + (51ull << 20));                        // 64 KB
    unsigned short* expE  = (unsigned short*)(ws + (52ull << 20));               // 52..116 MB
    if (ws_size < (116ull << 20)) {
        fprintf(stderr, "WS TOO SMALL: have %zu need %llu\n", ws_size, (116ull << 20));
    }

    // 1) xb = bf16(x)
    cast_x_kernel<<<dim3((Bn * Nn * Dn) / (8 * 256)), 256, 0, stream>>>(x, xb, Bn * Nn * Dn);
    // 2) WqkT = bf16([Wq; Wk]^T)
    transpose_cast_w<<<dim3(Hn / 64, Dn / 64, 2), 256, 0, stream>>>(Wq, Wk, WqkT);
    // 3) qk = xb @ [Wq|Wk] + [bq|bk]   (M=16384, N=1024, K=512) — 8 x 128 = 1024 blocks
    {
        const int gx = (2 * Hn) / 128, gy = (Bn * Nn) / 128;
        gemm_bt<0><<<dim3(gx * gy), 256, 0, stream>>>(
            xb, 0, Dn, WqkT, 0, Dn, qk, 0, bq, bk, Hn, nullptr,
            Bn * Nn, 2 * Hn, Dn, gx, gy);
    }
    // 4) expE = exp(q @ k^T) + col-sum partials (per batch; M=N=2048, K=512) — 16x16x8 = 2048 blocks
    {
        const int gx = Nn / 128, gy = Nn / 128;
        gemm_bt<1><<<dim3(gx * gy * Bn), 256, 0, stream>>>(
            qk, (long long)Nn * 2 * Hn, 2 * Hn,               // q = qk[:, 0:512]
            qk + Hn, (long long)Nn * 2 * Hn, 2 * Hn,          // k = qk[:, 512:1024]
            expE, (long long)Nn * Nn, nullptr, nullptr, 0, s_prt,
            Nn, Nn, Hn, gx, gy);
    }
    // 5) s[b][j] = sum of partials (16 m-blocks per batch)
    combine_s_kernel<<<dim3((Bn * Nn) / 256), 256, 0, stream>>>(s_prt, s, Nn / 128, Bn * Nn);
    // 6) xsT[b][d][j] = bf16(xb[b][j][d] / s[b][j])  (bf16 source; overwrites dead qk)
    transpose_scale_bf16<<<dim3(Dn / 64, Nn / 64, Bn), 256, 0, stream>>>(xb, xsT, s);
    // 7) out = expE @ xsT^T   (per batch; M=2048, N=512, K=2048) — 4 x 16 x 8 = 512 blocks
    {
        const int gx = Dn / 128, gy = Nn / 128;
        gemm_bt<2><<<dim3(gx * gy * Bn), 256, 0, stream>>>(
            expE, (long long)Nn * Nn, Nn, xsT, (long long)Dn * Nn, Nn,
            out, (long long)Nn * Dn, nullptr, nullptr, 0, nullptr,
            Nn, Dn, Nn, gx, gy);
    }
}